// Round 1
// 232.235 us; speedup vs baseline: 1.0727x; 1.0727x over previous
//
#include <hip/hip_runtime.h>
#include <math.h>

#define BB 32
#define AA 5
#define CC 80
#define HH 52
#define WW 52
#define NBOX 50
#define HWSZ (HH*WW)          // 2704
#define CELLS (AA*HWSZ)       // 13520

__constant__ float d_aw[AA] = {1.3221f, 3.19275f, 5.05587f, 9.47112f, 11.2364f};
__constant__ float d_ah[AA] = {1.73145f, 4.00944f, 8.09892f, 4.84053f, 10.0071f};

__device__ __forceinline__ float sig(float x) { return 1.f / (1.f + expf(-x)); }

// Single fused kernel. Each block (blockIdx.y = batch) recomputes the 50 box
// records for its batch in LDS (threads 0..49), then runs the per-cell loss.
// Records:
//  s_box: ax1, ax2, ay1, ay2   (corner gt box; zeros if invalid)
//  s_ac : gt area, cell-code   (code = a*HWSZ + gj*WW + gi; -1 if invalid)
//  s_t  : tx_t, ty_t, tw_t, th_t
//  s_m  : iou_gt, cls
// Last-writer semantics fall out of "win = last j with code==c" — the last
// matching j has no later collision, so CE/conf/coord dedup is automatic.
__global__ __launch_bounds__(256) void region_fused(const float* __restrict__ pred,
                                                    const float* __restrict__ target,
                                                    float* __restrict__ out) {
    __shared__ float4 s_box[NBOX];
    __shared__ float2 s_ac[NBOX];
    __shared__ float4 s_t[NBOX];
    __shared__ float2 s_m[NBOX];
    __shared__ float wsum[4];

    const int b = blockIdx.y;
    const int tid = threadIdx.x;

    if (tid < NBOX) {
        const float* t = target + ((size_t)b * NBOX + tid) * 5;
        float t0 = t[0], t1 = t[1], t2 = t[2], t3 = t[3], t4 = t[4];
        float gx = t1 * (float)WW, gy = t2 * (float)HH;
        float gw = t3 * (float)WW, gh = t4 * (float)HH;
        bool valid = t1 > 0.f;
        int best = 0; float bestv = -1.f;
        #pragma unroll
        for (int a = 0; a < AA; ++a) {
            float inter = fminf(gw, d_aw[a]) * fminf(gh, d_ah[a]);
            float uni = gw * gh + d_aw[a] * d_ah[a] - inter;
            float r = inter / uni;
            if (r > bestv) { bestv = r; best = a; }
        }
        int gi = (int)gx; gi = gi < 0 ? 0 : (gi > WW - 1 ? WW - 1 : gi);
        int gj = (int)gy; gj = gj < 0 ? 0 : (gj > HH - 1 ? HH - 1 : gj);

        // predicted box at (b, best, gj, gi) for iou_gt
        size_t bbase = ((size_t)(b * AA + best) * (CC + 5)) * HWSZ + (size_t)gj * WW + gi;
        float px = sig(pred[bbase]) + (float)gi;
        float py = sig(pred[bbase + HWSZ]) + (float)gj;
        float pw = expf(pred[bbase + 2 * HWSZ]) * d_aw[best];
        float ph = expf(pred[bbase + 3 * HWSZ]) * d_ah[best];

        float ax1 = gx - gw * 0.5f, ax2 = gx + gw * 0.5f;
        float ay1 = gy - gh * 0.5f, ay2 = gy + gh * 0.5f;
        float bx1 = px - pw * 0.5f, bx2 = px + pw * 0.5f;
        float by1 = py - ph * 0.5f, by2 = py + ph * 0.5f;
        float iw = fmaxf(fminf(ax2, bx2) - fmaxf(ax1, bx1), 0.f);
        float ih = fmaxf(fminf(ay2, by2) - fmaxf(ay1, by1), 0.f);
        float inter = iw * ih;
        float iou_gt = inter / (gw * gh + pw * ph - inter);

        if (valid) {
            s_box[tid] = make_float4(ax1, ax2, ay1, ay2);
            s_ac[tid]  = make_float2(gw * gh, (float)(best * HWSZ + gj * WW + gi));
        } else {
            s_box[tid] = make_float4(0.f, 0.f, 0.f, 0.f);
            s_ac[tid]  = make_float2(0.f, -1.f);
        }
        s_t[tid] = make_float4(gx - (float)gi, gy - (float)gj,
                               logf(gw / d_aw[best]), logf(gh / d_ah[best]));
        s_m[tid] = make_float2(iou_gt, t0);
    }
    __syncthreads();

    const int c = blockIdx.x * 256 + tid;
    float lsum = 0.f;
    if (c < CELLS) {
        int a = c / HWSZ;
        int rem = c - a * HWSZ;
        int hh = rem / WW;
        int wwi = rem - hh * WW;
        size_t base = ((size_t)(b * AA + a) * (CC + 5)) * HWSZ + rem;
        float p0 = pred[base];
        float p1 = pred[base + HWSZ];
        float p2 = pred[base + 2 * HWSZ];
        float p3 = pred[base + 3 * HWSZ];
        float p4 = pred[base + 4 * HWSZ];
        float tx = sig(p0);
        float ty = sig(p1);
        float conf = sig(p4);
        float bx = tx + (float)wwi;
        float by = ty + (float)hh;
        float bw = expf(p2) * d_aw[a];
        float bh = expf(p3) * d_ah[a];
        float px1 = bx - bw * 0.5f, px2 = bx + bw * 0.5f;
        float py1 = by - bh * 0.5f, py2 = by + bh * 0.5f;
        float parea = bw * bh;
        float cf = (float)c;   // cell code; exact in fp32 (< 2^24)

        float maxiou = 0.f;
        int win = -1;
        #pragma unroll 2
        for (int j = 0; j < NBOX; ++j) {
            float4 r0 = s_box[j];
            float2 r1 = s_ac[j];
            float iw2 = fmaxf(fminf(px2, r0.y) - fmaxf(px1, r0.x), 0.f);
            float ih2 = fmaxf(fminf(py2, r0.w) - fmaxf(py1, r0.z), 0.f);
            float inter2 = iw2 * ih2;
            float iou = inter2 / (parea + r1.x - inter2);
            maxiou = fmaxf(maxiou, iou);
            win = (r1.y == cf) ? j : win;   // last valid writer wins
        }

        float dx, dy, dw, dh, lconf;
        if (win >= 0) {
            float4 r2 = s_t[win];
            float2 r3 = s_m[win];
            dx = tx - r2.x; dy = ty - r2.y; dw = p2 - r2.z; dh = p3 - r2.w;
            float d = conf - r3.x;
            lconf = 2.5f * d * d;           // 0.5 * OBJECT_SCALE * (conf - iou_gt)^2
            // class cross-entropy at this winning cell (fires exactly once/cell)
            int tcls = (int)r3.y;
            tcls = tcls < 0 ? 0 : (tcls > CC - 1 ? CC - 1 : tcls);
            const float* lg = pred + base + 5 * (size_t)HWSZ;
            float mx = -INFINITY;
            #pragma unroll 8
            for (int cc = 0; cc < CC; ++cc) mx = fmaxf(mx, lg[(size_t)cc * HWSZ]);
            float s = 0.f;
            #pragma unroll 8
            for (int cc = 0; cc < CC; ++cc) s += expf(lg[(size_t)cc * HWSZ] - mx);
            lsum += (mx + logf(s)) - lg[(size_t)tcls * HWSZ];
        } else {
            dx = tx - 0.5f; dy = ty - 0.5f; dw = p2; dh = p3;
            float cm = (maxiou > 0.6f) ? 0.f : 1.f;
            lconf = 0.5f * cm * conf * conf;
        }
        lsum += 0.5f * (dx * dx + dy * dy + dw * dw + dh * dh) + lconf;
    }

    #pragma unroll
    for (int off = 32; off > 0; off >>= 1)
        lsum += __shfl_down(lsum, off, 64);
    int wave = tid >> 6;
    if ((tid & 63) == 0) wsum[wave] = lsum;
    __syncthreads();
    if (tid == 0) {
        atomicAdd(out, wsum[0] + wsum[1] + wsum[2] + wsum[3]);
    }
}

extern "C" void kernel_launch(void* const* d_in, const int* in_sizes, int n_in,
                              void* d_out, int out_size, void* d_ws, size_t ws_size,
                              hipStream_t stream) {
    const float* pred = (const float*)d_in[0];
    const float* target = (const float*)d_in[1];
    float* out = (float*)d_out;

    hipMemsetAsync(out, 0, sizeof(float) * out_size, stream);
    dim3 grid((CELLS + 255) / 256, BB);
    region_fused<<<grid, dim3(256), 0, stream>>>(pred, target, out);
}

// Round 2
// 204.728 us; speedup vs baseline: 1.2169x; 1.1344x over previous
//
#include <hip/hip_runtime.h>
#include <math.h>

#define BB 32
#define AA 5
#define CC 80
#define HH 52
#define WW 52
#define NBOX 50
#define HWSZ (HH*WW)          // 2704
#define CELLS (AA*HWSZ)       // 13520

__constant__ float d_aw[AA] = {1.3221f, 3.19275f, 5.05587f, 9.47112f, 11.2364f};
__constant__ float d_ah[AA] = {1.73145f, 4.00944f, 8.09892f, 4.84053f, 10.0071f};

__device__ __forceinline__ float sig(float x) { return 1.f / (1.f + expf(-x)); }

__device__ __forceinline__ float wave_max(float v) {
    #pragma unroll
    for (int off = 32; off > 0; off >>= 1) v = fmaxf(v, __shfl_xor(v, off, 64));
    return v;
}
__device__ __forceinline__ float wave_sum(float v) {
    #pragma unroll
    for (int off = 32; off > 0; off >>= 1) v += __shfl_xor(v, off, 64);
    return v;
}

// Single fused kernel. blockIdx.y = batch. Threads 0..49 rebuild the 50 box
// records in LDS, then one thread per (a,h,w) cell computes the loss.
// Records:
//  s_box: ax1, ax2, ay1, ay2       (corner gt box; zeros if invalid)
//  s_ac : 0.375*area, cell-code    (code = a*HWSZ + gj*WW + gi; -1 if invalid)
//  s_t  : tx_t, ty_t, tw_t, th_t
//  s_m  : iou_gt, cls
// Division-free sil-test: iou>0.6  <=>  inter > 0.375*(parea+area_j)
//                                  <=>  (inter - 0.375*parea) > 0.375*area_j
// Last-writer dedup falls out of "win = last j with code==c".
__global__ __launch_bounds__(256) void region_fused(const float* __restrict__ pred,
                                                    const float* __restrict__ target,
                                                    float* __restrict__ out) {
    __shared__ float4 s_box[NBOX];
    __shared__ float2 s_ac[NBOX];
    __shared__ float4 s_t[NBOX];
    __shared__ float2 s_m[NBOX];
    __shared__ float wsum[4];

    const int b = blockIdx.y;
    const int tid = threadIdx.x;
    const int lane = tid & 63;

    if (tid < NBOX) {
        const float* t = target + ((size_t)b * NBOX + tid) * 5;
        float t0 = t[0], t1 = t[1], t2 = t[2], t3 = t[3], t4 = t[4];
        float gx = t1 * (float)WW, gy = t2 * (float)HH;
        float gw = t3 * (float)WW, gh = t4 * (float)HH;
        bool valid = t1 > 0.f;
        int best = 0; float bestv = -1.f;
        #pragma unroll
        for (int a = 0; a < AA; ++a) {
            float inter = fminf(gw, d_aw[a]) * fminf(gh, d_ah[a]);
            float uni = gw * gh + d_aw[a] * d_ah[a] - inter;
            float r = inter / uni;
            if (r > bestv) { bestv = r; best = a; }
        }
        int gi = (int)gx; gi = gi < 0 ? 0 : (gi > WW - 1 ? WW - 1 : gi);
        int gj = (int)gy; gj = gj < 0 ? 0 : (gj > HH - 1 ? HH - 1 : gj);

        // predicted box at (b, best, gj, gi) for iou_gt
        size_t bbase = ((size_t)(b * AA + best) * (CC + 5)) * HWSZ + (size_t)gj * WW + gi;
        float px = sig(pred[bbase]) + (float)gi;
        float py = sig(pred[bbase + HWSZ]) + (float)gj;
        float pw = expf(pred[bbase + 2 * HWSZ]) * d_aw[best];
        float ph = expf(pred[bbase + 3 * HWSZ]) * d_ah[best];

        float ax1 = gx - gw * 0.5f, ax2 = gx + gw * 0.5f;
        float ay1 = gy - gh * 0.5f, ay2 = gy + gh * 0.5f;
        float bx1 = px - pw * 0.5f, bx2 = px + pw * 0.5f;
        float by1 = py - ph * 0.5f, by2 = py + ph * 0.5f;
        float iw = fmaxf(fminf(ax2, bx2) - fmaxf(ax1, bx1), 0.f);
        float ih = fmaxf(fminf(ay2, by2) - fmaxf(ay1, by1), 0.f);
        float inter = iw * ih;
        float iou_gt = inter / (gw * gh + pw * ph - inter);

        if (valid) {
            s_box[tid] = make_float4(ax1, ax2, ay1, ay2);
            s_ac[tid]  = make_float2(0.375f * gw * gh,
                                     (float)(best * HWSZ + gj * WW + gi));
        } else {
            s_box[tid] = make_float4(0.f, 0.f, 0.f, 0.f);
            s_ac[tid]  = make_float2(0.f, -1.f);
        }
        s_t[tid] = make_float4(gx - (float)gi, gy - (float)gj,
                               logf(gw / d_aw[best]), logf(gh / d_ah[best]));
        s_m[tid] = make_float2(iou_gt, t0);
    }
    __syncthreads();

    const int c = blockIdx.x * 256 + tid;
    float lsum = 0.f;
    int win = -1;
    int a = 0, rem = 0, tcls = 0;
    if (c < CELLS) {
        a = c / HWSZ;
        rem = c - a * HWSZ;
        int hh = rem / WW;
        int wwi = rem - hh * WW;
        size_t base = ((size_t)(b * AA + a) * (CC + 5)) * HWSZ + rem;
        float p0 = pred[base];
        float p1 = pred[base + HWSZ];
        float p2 = pred[base + 2 * HWSZ];
        float p3 = pred[base + 3 * HWSZ];
        float p4 = pred[base + 4 * HWSZ];
        float tx = sig(p0);
        float ty = sig(p1);
        float conf = sig(p4);
        float bx = tx + (float)wwi;
        float by = ty + (float)hh;
        float bw = expf(p2) * d_aw[a];
        float bh = expf(p3) * d_ah[a];
        float px1 = bx - bw * 0.5f, px2 = bx + bw * 0.5f;
        float py1 = by - bh * 0.5f, py2 = by + bh * 0.5f;
        float tp = 0.375f * (bw * bh);      // 0.375 * parea
        float cf = (float)c;                // cell code; exact in fp32

        bool hit = false;
        #pragma unroll 5
        for (int j = 0; j < NBOX; ++j) {
            float4 r0 = s_box[j];
            float2 r1 = s_ac[j];
            float iw2 = fmaxf(fminf(px2, r0.y) - fmaxf(px1, r0.x), 0.f);
            float ih2 = fmaxf(fminf(py2, r0.w) - fmaxf(py1, r0.z), 0.f);
            float inter2 = iw2 * ih2;
            hit = hit | ((inter2 - tp) > r1.x);   // iou_j > 0.6
            win = (r1.y == cf) ? j : win;         // last valid writer wins
        }

        float dx, dy, dw, dh, lconf;
        if (win >= 0) {
            float4 r2 = s_t[win];
            float2 r3 = s_m[win];
            dx = tx - r2.x; dy = ty - r2.y; dw = p2 - r2.z; dh = p3 - r2.w;
            float d = conf - r3.x;
            lconf = 2.5f * d * d;           // 0.5 * OBJECT_SCALE * (conf - iou_gt)^2
            int tc = (int)r3.y;
            tcls = tc < 0 ? 0 : (tc > CC - 1 ? CC - 1 : tc);
        } else {
            dx = tx - 0.5f; dy = ty - 0.5f; dw = p2; dh = p3;
            lconf = hit ? 0.f : 0.5f * conf * conf;
        }
        lsum = 0.5f * (dx * dx + dy * dy + dw * dw + dh * dh) + lconf;
    }

    // Wave-cooperative class cross-entropy over the (rare) winning cells.
    // All 64 lanes share each winner's 80-logit logsumexp.
    unsigned long long mask = __ballot(win >= 0);
    while (mask) {
        int src = __ffsll(mask) - 1;
        mask &= mask - 1;
        int wa   = __shfl(a, src, 64);
        int wrem = __shfl(rem, src, 64);
        int wt   = __shfl(tcls, src, 64);
        size_t cbase = ((size_t)(b * AA + wa) * (CC + 5) + 5) * HWSZ + (size_t)wrem;
        float v1 = pred[cbase + (size_t)lane * HWSZ];
        float v2 = (lane < CC - 64) ? pred[cbase + (size_t)(lane + 64) * HWSZ]
                                    : -INFINITY;
        float mx = wave_max(fmaxf(v1, v2));
        float s = expf(v1 - mx) + ((lane < CC - 64) ? expf(v2 - mx) : 0.f);
        s = wave_sum(s);
        float vt = ((lane == wt) ? v1 : 0.f) + ((lane + 64 == wt) ? v2 : 0.f);
        vt = wave_sum(vt);
        if (lane == src) lsum += (mx + logf(s)) - vt;
    }

    #pragma unroll
    for (int off = 32; off > 0; off >>= 1)
        lsum += __shfl_down(lsum, off, 64);
    int wave = tid >> 6;
    if (lane == 0) wsum[wave] = lsum;
    __syncthreads();
    if (tid == 0) {
        atomicAdd(out, wsum[0] + wsum[1] + wsum[2] + wsum[3]);
    }
}

extern "C" void kernel_launch(void* const* d_in, const int* in_sizes, int n_in,
                              void* d_out, int out_size, void* d_ws, size_t ws_size,
                              hipStream_t stream) {
    const float* pred = (const float*)d_in[0];
    const float* target = (const float*)d_in[1];
    float* out = (float*)d_out;

    hipMemsetAsync(out, 0, sizeof(float) * out_size, stream);
    dim3 grid((CELLS + 255) / 256, BB);
    region_fused<<<grid, dim3(256), 0, stream>>>(pred, target, out);
}

// Round 3
// 203.252 us; speedup vs baseline: 1.2257x; 1.0073x over previous
//
#include <hip/hip_runtime.h>
#include <math.h>

#define BB 32
#define AA 5
#define CC 80
#define HH 52
#define WW 52
#define NBOX 50
#define HWSZ (HH*WW)          // 2704
#define CELLS (AA*HWSZ)       // 13520
#define NCH 4                 // cells per thread
#define CSTRIDE (16*256)      // 4096: chunk stride, keeps coalescing

__constant__ float d_aw[AA] = {1.3221f, 3.19275f, 5.05587f, 9.47112f, 11.2364f};
__constant__ float d_ah[AA] = {1.73145f, 4.00944f, 8.09892f, 4.84053f, 10.0071f};

__device__ __forceinline__ float sig(float x) { return 1.f / (1.f + expf(-x)); }

__device__ __forceinline__ float wave_max(float v) {
    #pragma unroll
    for (int off = 32; off > 0; off >>= 1) v = fmaxf(v, __shfl_xor(v, off, 64));
    return v;
}
__device__ __forceinline__ float wave_sum(float v) {
    #pragma unroll
    for (int off = 32; off > 0; off >>= 1) v += __shfl_xor(v, off, 64);
    return v;
}

// Single fused kernel. blockIdx.y = batch, 16 x-blocks (512 total = 2/CU).
// Threads 0..49 rebuild the 50 box records in LDS, then each thread handles
// NCH=4 cells (c = blkx*256+tid + k*4096), amortizing the per-box LDS
// broadcast reads across 4 IoU tests.
// Records:
//  s_box: ax1, ax2, ay1, ay2       (corner gt box; zeros if invalid)
//  s_ac : 0.375*area, cell-code    (code = a*HWSZ + gj*WW + gi; -1 if invalid)
//  s_t  : tx_t, ty_t, tw_t, th_t
//  s_m  : iou_gt, cls
// Division-free sil-test: iou>0.6  <=>  (inter - 0.375*parea) > 0.375*area_j
// Last-writer dedup falls out of "win = last j with code==c".
__global__ __launch_bounds__(256) void region_fused(const float* __restrict__ pred,
                                                    const float* __restrict__ target,
                                                    float* __restrict__ out) {
    __shared__ float4 s_box[NBOX];
    __shared__ float2 s_ac[NBOX];
    __shared__ float4 s_t[NBOX];
    __shared__ float2 s_m[NBOX];
    __shared__ float wsum[4];

    const int b = blockIdx.y;
    const int tid = threadIdx.x;
    const int lane = tid & 63;

    if (tid < NBOX) {
        const float* t = target + ((size_t)b * NBOX + tid) * 5;
        float t0 = t[0], t1 = t[1], t2 = t[2], t3 = t[3], t4 = t[4];
        float gx = t1 * (float)WW, gy = t2 * (float)HH;
        float gw = t3 * (float)WW, gh = t4 * (float)HH;
        bool valid = t1 > 0.f;
        int best = 0; float bestv = -1.f;
        #pragma unroll
        for (int a = 0; a < AA; ++a) {
            float inter = fminf(gw, d_aw[a]) * fminf(gh, d_ah[a]);
            float uni = gw * gh + d_aw[a] * d_ah[a] - inter;
            float r = inter / uni;
            if (r > bestv) { bestv = r; best = a; }
        }
        int gi = (int)gx; gi = gi < 0 ? 0 : (gi > WW - 1 ? WW - 1 : gi);
        int gj = (int)gy; gj = gj < 0 ? 0 : (gj > HH - 1 ? HH - 1 : gj);

        // predicted box at (b, best, gj, gi) for iou_gt
        size_t bbase = ((size_t)(b * AA + best) * (CC + 5)) * HWSZ + (size_t)gj * WW + gi;
        float px = sig(pred[bbase]) + (float)gi;
        float py = sig(pred[bbase + HWSZ]) + (float)gj;
        float pw = expf(pred[bbase + 2 * HWSZ]) * d_aw[best];
        float ph = expf(pred[bbase + 3 * HWSZ]) * d_ah[best];

        float ax1 = gx - gw * 0.5f, ax2 = gx + gw * 0.5f;
        float ay1 = gy - gh * 0.5f, ay2 = gy + gh * 0.5f;
        float bx1 = px - pw * 0.5f, bx2 = px + pw * 0.5f;
        float by1 = py - ph * 0.5f, by2 = py + ph * 0.5f;
        float iw = fmaxf(fminf(ax2, bx2) - fmaxf(ax1, bx1), 0.f);
        float ih = fmaxf(fminf(ay2, by2) - fmaxf(ay1, by1), 0.f);
        float inter = iw * ih;
        float iou_gt = inter / (gw * gh + pw * ph - inter);

        if (valid) {
            s_box[tid] = make_float4(ax1, ax2, ay1, ay2);
            s_ac[tid]  = make_float2(0.375f * gw * gh,
                                     (float)(best * HWSZ + gj * WW + gi));
        } else {
            s_box[tid] = make_float4(0.f, 0.f, 0.f, 0.f);
            s_ac[tid]  = make_float2(0.f, -1.f);
        }
        s_t[tid] = make_float4(gx - (float)gi, gy - (float)gj,
                               logf(gw / d_aw[best]), logf(gh / d_ah[best]));
        s_m[tid] = make_float2(iou_gt, t0);
    }
    __syncthreads();

    const int c0 = blockIdx.x * 256 + tid;

    float px1[NCH], px2[NCH], py1[NCH], py2[NCH], tp[NCH], cf[NCH];
    float p2s[NCH], p3s[NCH], txs[NCH], tys[NCH], cfs[NCH];
    int aA[NCH], remA[NCH], win[NCH], tcl[NCH];
    bool hit[NCH], act[NCH];

    float lsum = 0.f;

    #pragma unroll
    for (int k = 0; k < NCH; ++k) {
        int c = c0 + k * CSTRIDE;
        act[k] = (c < CELLS);
        win[k] = -1;
        hit[k] = false;
        tcl[k] = 0;
        int cc = act[k] ? c : 0;
        int a = cc / HWSZ;
        int rem = cc - a * HWSZ;
        aA[k] = a; remA[k] = rem;
        int hh = rem / WW;
        int wwi = rem - hh * WW;
        float p0 = 0.f, p1 = 0.f, p2 = 0.f, p3 = 0.f, p4 = 0.f;
        if (act[k]) {
            size_t base = ((size_t)(b * AA + a) * (CC + 5)) * HWSZ + rem;
            p0 = pred[base];
            p1 = pred[base + HWSZ];
            p2 = pred[base + 2 * HWSZ];
            p3 = pred[base + 3 * HWSZ];
            p4 = pred[base + 4 * HWSZ];
        }
        float tx = sig(p0);
        float ty = sig(p1);
        float conf = sig(p4);
        float bx = tx + (float)wwi;
        float by = ty + (float)hh;
        float bw = expf(p2) * d_aw[a];
        float bh = expf(p3) * d_ah[a];
        px1[k] = bx - bw * 0.5f; px2[k] = bx + bw * 0.5f;
        py1[k] = by - bh * 0.5f; py2[k] = by + bh * 0.5f;
        tp[k] = 0.375f * (bw * bh);
        cf[k] = act[k] ? (float)c : -2.f;   // -2 never matches a code
        p2s[k] = p2; p3s[k] = p3; txs[k] = tx; tys[k] = ty; cfs[k] = conf;
    }

    #pragma unroll 2
    for (int j = 0; j < NBOX; ++j) {
        float4 r0 = s_box[j];
        float2 r1 = s_ac[j];
        #pragma unroll
        for (int k = 0; k < NCH; ++k) {
            float iw2 = fmaxf(fminf(px2[k], r0.y) - fmaxf(px1[k], r0.x), 0.f);
            float ih2 = fmaxf(fminf(py2[k], r0.w) - fmaxf(py1[k], r0.z), 0.f);
            float inter2 = iw2 * ih2;
            hit[k] = hit[k] | ((inter2 - tp[k]) > r1.x);   // iou_j > 0.6
            win[k] = (r1.y == cf[k]) ? j : win[k];          // last writer wins
        }
    }

    #pragma unroll
    for (int k = 0; k < NCH; ++k) {
        if (!act[k]) continue;
        float tx = txs[k], ty = tys[k], p2 = p2s[k], p3 = p3s[k], conf = cfs[k];
        float dx, dy, dw, dh, lconf;
        if (win[k] >= 0) {
            float4 r2 = s_t[win[k]];
            float2 r3 = s_m[win[k]];
            dx = tx - r2.x; dy = ty - r2.y; dw = p2 - r2.z; dh = p3 - r2.w;
            float d = conf - r3.x;
            lconf = 2.5f * d * d;           // 0.5 * OBJECT_SCALE * (conf-iou_gt)^2
            int tc = (int)r3.y;
            tcl[k] = tc < 0 ? 0 : (tc > CC - 1 ? CC - 1 : tc);
        } else {
            dx = tx - 0.5f; dy = ty - 0.5f; dw = p2; dh = p3;
            lconf = hit[k] ? 0.f : 0.5f * conf * conf;
        }
        lsum += 0.5f * (dx * dx + dy * dy + dw * dw + dh * dh) + lconf;
    }

    // Wave-cooperative class cross-entropy over the (rare) winning cells.
    #pragma unroll
    for (int k = 0; k < NCH; ++k) {
        unsigned long long mask = __ballot(win[k] >= 0);
        while (mask) {
            int src = __ffsll(mask) - 1;
            mask &= mask - 1;
            int wa   = __shfl(aA[k], src, 64);
            int wrem = __shfl(remA[k], src, 64);
            int wt   = __shfl(tcl[k], src, 64);
            size_t cbase = ((size_t)(b * AA + wa) * (CC + 5) + 5) * HWSZ + (size_t)wrem;
            float v1 = pred[cbase + (size_t)lane * HWSZ];
            float v2 = (lane < CC - 64) ? pred[cbase + (size_t)(lane + 64) * HWSZ]
                                        : -INFINITY;
            float mx = wave_max(fmaxf(v1, v2));
            float s = expf(v1 - mx) + ((lane < CC - 64) ? expf(v2 - mx) : 0.f);
            s = wave_sum(s);
            float vt = ((lane == wt) ? v1 : 0.f) + ((lane + 64 == wt) ? v2 : 0.f);
            vt = wave_sum(vt);
            if (lane == src) lsum += (mx + logf(s)) - vt;
        }
    }

    #pragma unroll
    for (int off = 32; off > 0; off >>= 1)
        lsum += __shfl_down(lsum, off, 64);
    int wave = tid >> 6;
    if (lane == 0) wsum[wave] = lsum;
    __syncthreads();
    if (tid == 0) {
        atomicAdd(out, wsum[0] + wsum[1] + wsum[2] + wsum[3]);
    }
}

extern "C" void kernel_launch(void* const* d_in, const int* in_sizes, int n_in,
                              void* d_out, int out_size, void* d_ws, size_t ws_size,
                              hipStream_t stream) {
    const float* pred = (const float*)d_in[0];
    const float* target = (const float*)d_in[1];
    float* out = (float*)d_out;

    hipMemsetAsync(out, 0, sizeof(float) * out_size, stream);
    dim3 grid(16, BB);
    region_fused<<<grid, dim3(256), 0, stream>>>(pred, target, out);
}